// Round 2
// baseline (872.364 us; speedup 1.0000x reference)
//
#include <hip/hip_runtime.h>
#include <hip/hip_bf16.h>

typedef __attribute__((ext_vector_type(8))) short bf16x8;
typedef __attribute__((ext_vector_type(4))) float f32x4;
typedef __attribute__((ext_vector_type(16))) float f32x16;

#define NTOK 50
#define CDIM 256
#define NH   8
#define SCALE 0.17677669529663687f   // 1/sqrt(32)
#define MFMA32(a,b,c) __builtin_amdgcn_mfma_f32_32x32x16_bf16(a,b,c,0,0,0)
#define Z16 {0.f,0.f,0.f,0.f,0.f,0.f,0.f,0.f,0.f,0.f,0.f,0.f,0.f,0.f,0.f,0.f}

__device__ __forceinline__ unsigned short f2bf(float f) {
  union { __hip_bfloat16 h; unsigned short u; } c;
  c.h = __float2bfloat16(f);  // RNE
  return c.u;
}
__device__ __forceinline__ unsigned pk2(float a, float b) {
  return (unsigned)f2bf(a) | ((unsigned)f2bf(b) << 16);
}

// Exchange primitive: produced 32x32 C-tile packed as pk[4] uint2 (pk[grp] = regs
// grp*4+rr over axis value rr+8*grp+4*half). Returns the MFMA A/B fragment for
// axis chunk c1 (values c1*16 + myh*8 + j). Derivation: grp = 2*c1 + myh (dest),
// source half = j>>2. 2 shfl + 8 cndmask.
__device__ __forceinline__ bf16x8 xchg(uint2 pkA, uint2 pkB, int myh) {
  unsigned ownx = myh ? pkB.x : pkA.x, owny = myh ? pkB.y : pkA.y;
  unsigned crx  = myh ? pkA.x : pkB.x, cry  = myh ? pkA.y : pkB.y;
  crx = (unsigned)__shfl_xor((int)crx, 32);
  cry = (unsigned)__shfl_xor((int)cry, 32);
  union { bf16x8 v; unsigned u[4]; } r;
  r.u[0] = myh ? crx : ownx;
  r.u[1] = myh ? cry : owny;
  r.u[2] = myh ? ownx : crx;
  r.u[3] = myh ? owny : cry;
  return r.v;
}

// Swizzled 32KB tile: phys_byte(row, col_byte) = row*512 + ((col_byte>>4) ^ (row&31))*16 + (col_byte&15)
__device__ __forceinline__ bf16x8 ld_tile(const char* base, int row, int kc, int myh) {
  int byte = row * 512 + ((((kc << 1) | myh) ^ (row & 31)) << 4);
  return *(const bf16x8*)(base + byte);
}

// prep: W -> bf16 in FRAGMENT order (coalesced dwordx4 streams in main kernel),
// Q rows pre-scaled; biasT in register-order [h][kt][qt][grp][hh][l31][rr] with
// key-mask folded in.
__global__ void prep_kernel(const float* __restrict__ qkv_w, const float* __restrict__ proj_w,
                            const float* __restrict__ bias_table, const int* __restrict__ rel_idx,
                            unsigned short* __restrict__ wq, unsigned short* __restrict__ wp,
                            float* __restrict__ biasT) {
  int i = blockIdx.x * 256 + (int)threadIdx.x;
  if (i < 768 * 256) {
    int row = i >> 8, col = i & 255;
    int mat = row >> 8, h = (row >> 5) & 7, r31 = row & 31;
    int kc = col >> 4, hh = (col >> 3) & 1, j = col & 7;
    int dst = ((((mat * 8 + h) * 16 + kc) * 2 + hh) * 32 + r31) * 8 + j;
    float v = qkv_w[i];
    if (mat == 0) v *= SCALE;
    wq[dst] = f2bf(v);
  }
  if (i < 256 * 256) {
    int row = i >> 8, col = i & 255;
    int wv = row >> 5, r31 = row & 31;
    int kc = col >> 4, hh = (col >> 3) & 1, j = col & 7;
    int dst = (((wv * 16 + kc) * 2 + hh) * 32 + r31) * 8 + j;
    wp[dst] = f2bf(proj_w[i]);
  }
  if (i < 32768) {
    int h = i >> 12, kt = (i >> 11) & 1, qt = (i >> 10) & 1;
    int grp = (i >> 8) & 3, hh = (i >> 7) & 1, l31 = (i >> 2) & 31, rr = i & 3;
    int key = kt * 32 + grp * 8 + hh * 4 + rr;
    int query = qt * 32 + l31;
    float v;
    if (key >= NTOK) v = -1e30f;                               // padded keys: softmax mask
    else if (query == 0 || key == 0 || query >= NTOK) v = 0.f; // region token row/col
    else v = bias_table[rel_idx[(query - 1) * 49 + (key - 1)] * NH + h];
    biasT[i] = v;
  }
}

__global__ __launch_bounds__(512, 4)
void mhsa_kernel(const float* __restrict__ x, const unsigned short* __restrict__ wq,
                 const unsigned short* __restrict__ wp, const float* __restrict__ biasT,
                 const float* __restrict__ qkv_b, const float* __restrict__ proj_b,
                 float* __restrict__ out) {
  __shared__ uint4 shbuf[2048];            // 32 KB: x tile, later aliased as O tile
  char* base = (char*)shbuf;

  const int b = blockIdx.x;
  const int tid = (int)threadIdx.x;
  const int w = tid >> 6;                  // wave id = head
  const int lane = tid & 63;
  const int l31 = lane & 31;
  const int myh = lane >> 5;

  // ---- stage x -> swizzled bf16 LDS tile (rows >= 50 zeroed) ----
  {
    const float* xb = x + (size_t)b * NTOK * CDIM;
    #pragma unroll
    for (int i = 0; i < 8; ++i) {
      int flat = i * 512 + tid;
      int row = flat >> 6, c4 = flat & 63;
      uint2 pv = make_uint2(0u, 0u);
      if (row < NTOK) {
        float4 v = *(const float4*)&xb[row * CDIM + c4 * 4];
        pv.x = pk2(v.x, v.y);
        pv.y = pk2(v.z, v.w);
      }
      int byte = row * 512 + ((((c4 >> 1) ^ (row & 31)) << 4) | ((c4 & 1) << 3));
      *(uint2*)(base + byte) = pv;
    }
  }
  __syncthreads();

  // ---- fused Q+K GEMM (shared x fragments), A = W (frag-ordered), B = x^T ----
  const unsigned short* wQb = wq + (size_t)w * 8192;
  const unsigned short* wKb = wq + 65536 + (size_t)w * 8192;
  const unsigned short* wVb = wq + 131072 + (size_t)w * 8192;

  f32x16 accQ0 = Z16, accQ1 = Z16, accK0 = Z16, accK1 = Z16;
  #pragma unroll
  for (int kc = 0; kc < 16; ++kc) {
    bf16x8 wqf = *(const bf16x8*)&wQb[(kc * 2 + myh) * 256 + l31 * 8];
    bf16x8 wkf = *(const bf16x8*)&wKb[(kc * 2 + myh) * 256 + l31 * 8];
    bf16x8 x0 = ld_tile(base, l31, kc, myh);
    bf16x8 x1 = ld_tile(base, 32 + l31, kc, myh);
    accQ0 = MFMA32(wqf, x0, accQ0);
    accK0 = MFMA32(wkf, x0, accK0);
    accQ1 = MFMA32(wqf, x1, accQ1);
    accK1 = MFMA32(wkf, x1, accK1);
  }
  #pragma unroll
  for (int r = 0; r < 16; ++r) {
    int f = (r & 3) + 8 * (r >> 2) + 4 * myh;
    float bq = qkv_b[w * 32 + f] * SCALE;
    float bk = qkv_b[CDIM + w * 32 + f];
    accQ0[r] += bq; accQ1[r] += bq;
    accK0[r] += bk; accK1[r] += bk;
  }
  uint2 pq0[4], pq1[4], pk0[4], pk1[4];
  #pragma unroll
  for (int gI = 0; gI < 4; ++gI) {
    pq0[gI] = make_uint2(pk2(accQ0[4*gI], accQ0[4*gI+1]), pk2(accQ0[4*gI+2], accQ0[4*gI+3]));
    pq1[gI] = make_uint2(pk2(accQ1[4*gI], accQ1[4*gI+1]), pk2(accQ1[4*gI+2], accQ1[4*gI+3]));
    pk0[gI] = make_uint2(pk2(accK0[4*gI], accK0[4*gI+1]), pk2(accK0[4*gI+2], accK0[4*gI+3]));
    pk1[gI] = make_uint2(pk2(accK1[4*gI], accK1[4*gI+1]), pk2(accK1[4*gI+2], accK1[4*gI+3]));
  }
  bf16x8 Qf[2][2], Kf[2][2];
  Qf[0][0] = xchg(pq0[0], pq0[1], myh);  Qf[0][1] = xchg(pq0[2], pq0[3], myh);
  Qf[1][0] = xchg(pq1[0], pq1[1], myh);  Qf[1][1] = xchg(pq1[2], pq1[3], myh);
  Kf[0][0] = xchg(pk0[0], pk0[1], myh);  Kf[0][1] = xchg(pk0[2], pk0[3], myh);
  Kf[1][0] = xchg(pk1[0], pk1[1], myh);  Kf[1][1] = xchg(pk1[2], pk1[3], myh);

  // ---- V GEMM: A = x (rows=tokens), B = Wv^T (cols=d) ----
  f32x16 accV0 = Z16, accV1 = Z16;
  #pragma unroll
  for (int kc = 0; kc < 16; ++kc) {
    bf16x8 wvf = *(const bf16x8*)&wVb[(kc * 2 + myh) * 256 + l31 * 8];
    accV0 = MFMA32(ld_tile(base, l31, kc, myh), wvf, accV0);
    accV1 = MFMA32(ld_tile(base, 32 + l31, kc, myh), wvf, accV1);
  }
  {
    float bv = qkv_b[2 * CDIM + w * 32 + l31];
    #pragma unroll
    for (int r = 0; r < 16; ++r) { accV0[r] += bv; accV1[r] += bv; }
  }
  uint2 pv0[4], pv1[4];
  #pragma unroll
  for (int gI = 0; gI < 4; ++gI) {
    pv0[gI] = make_uint2(pk2(accV0[4*gI], accV0[4*gI+1]), pk2(accV0[4*gI+2], accV0[4*gI+3]));
    pv1[gI] = make_uint2(pk2(accV1[4*gI], accV1[4*gI+1]), pk2(accV1[4*gI+2], accV1[4*gI+3]));
  }
  bf16x8 Vf[4];
  Vf[0] = xchg(pv0[0], pv0[1], myh);  Vf[1] = xchg(pv0[2], pv0[3], myh);
  Vf[2] = xchg(pv1[0], pv1[1], myh);  Vf[3] = xchg(pv1[2], pv1[3], myh);

  // ---- per query-tile: S^T = K*Q^T (+bias) -> softmax (lane-local) -> P -> O = P*V ----
  f32x16 O[2];
  #pragma unroll
  for (int qt = 0; qt < 2; ++qt) {
    f32x16 s0 = Z16, s1 = Z16;
    s0 = MFMA32(Kf[0][0], Qf[qt][0], s0);  s0 = MFMA32(Kf[0][1], Qf[qt][1], s0);
    s1 = MFMA32(Kf[1][0], Qf[qt][0], s1);  s1 = MFMA32(Kf[1][1], Qf[qt][1], s1);
    // bias add (frag-ordered, coalesced dwordx4)
    #pragma unroll
    for (int kt = 0; kt < 2; ++kt) {
      const float* bT = biasT + (size_t)(((w * 2 + kt) * 2 + qt) * 1024);
      #pragma unroll
      for (int gI = 0; gI < 4; ++gI) {
        f32x4 bv = *(const f32x4*)&bT[(gI * 2 + myh) * 128 + l31 * 4];
        if (kt == 0) { s0[4*gI] += bv[0]; s0[4*gI+1] += bv[1]; s0[4*gI+2] += bv[2]; s0[4*gI+3] += bv[3]; }
        else         { s1[4*gI] += bv[0]; s1[4*gI+1] += bv[1]; s1[4*gI+2] += bv[2]; s1[4*gI+3] += bv[3]; }
      }
    }
    // softmax over 64 keys: 32 lane-local + one cross-half shfl
    float mx = -3e38f;
    #pragma unroll
    for (int r = 0; r < 16; ++r) { mx = fmaxf(mx, s0[r]); mx = fmaxf(mx, s1[r]); }
    mx = fmaxf(mx, __shfl_xor(mx, 32));
    float sum = 0.f;
    #pragma unroll
    for (int r = 0; r < 16; ++r) {
      float e0 = __expf(s0[r] - mx); s0[r] = e0; sum += e0;
      float e1 = __expf(s1[r] - mx); s1[r] = e1; sum += e1;
    }
    sum += __shfl_xor(sum, 32);
    float inv = 1.f / sum;
    uint2 pp0[4], pp1[4];
    #pragma unroll
    for (int gI = 0; gI < 4; ++gI) {
      pp0[gI] = make_uint2(pk2(s0[4*gI]*inv, s0[4*gI+1]*inv), pk2(s0[4*gI+2]*inv, s0[4*gI+3]*inv));
      pp1[gI] = make_uint2(pk2(s1[4*gI]*inv, s1[4*gI+1]*inv), pk2(s1[4*gI+2]*inv, s1[4*gI+3]*inv));
    }
    bf16x8 Pf0 = xchg(pp0[0], pp0[1], myh), Pf1 = xchg(pp0[2], pp0[3], myh);
    bf16x8 Pf2 = xchg(pp1[0], pp1[1], myh), Pf3 = xchg(pp1[2], pp1[3], myh);
    f32x16 o = Z16;
    o = MFMA32(Pf0, Vf[0], o);
    o = MFMA32(Pf1, Vf[1], o);
    o = MFMA32(Pf2, Vf[2], o);
    o = MFMA32(Pf3, Vf[3], o);
    O[qt] = o;
  }

  __syncthreads();   // all waves done reading x -> safe to overwrite with O
  // ---- O -> swizzled LDS tile (cols w*32 + l31), bf16 ----
  #pragma unroll
  for (int r = 0; r < 16; ++r) {
    int t0 = (r & 3) + 8 * (r >> 2) + 4 * myh;
    int slotbase = (w << 2) | (l31 >> 3);
    int byte0 = t0 * 512 + (((slotbase ^ (t0 & 31)) << 4) | ((l31 & 7) << 1));
    *(unsigned short*)(base + byte0) = f2bf(O[0][r]);
    int t1 = 32 + t0;
    int byte1 = t1 * 512 + (((slotbase ^ (t1 & 31)) << 4) | ((l31 & 7) << 1));
    *(unsigned short*)(base + byte1) = f2bf(O[1][r]);
  }
  __syncthreads();

  // ---- proj: out = O * Wp^T + pb; wave owns e-cols [32w, 32w+32) ----
  const unsigned short* wPb = wp + (size_t)w * 8192;
  f32x16 po0 = Z16, po1 = Z16;
  #pragma unroll
  for (int kc = 0; kc < 16; ++kc) {
    bf16x8 wpf = *(const bf16x8*)&wPb[(kc * 2 + myh) * 256 + l31 * 8];
    po0 = MFMA32(ld_tile(base, l31, kc, myh), wpf, po0);
    po1 = MFMA32(ld_tile(base, 32 + l31, kc, myh), wpf, po1);
  }
  float pb = proj_b[w * 32 + l31];
  #pragma unroll
  for (int r = 0; r < 16; ++r) {
    int t0 = (r & 3) + 8 * (r >> 2) + 4 * myh;
    if (t0 < NTOK) out[((size_t)b * NTOK + t0) * CDIM + w * 32 + l31] = po0[r] + pb;
    int t1 = 32 + t0;
    if (t1 < NTOK) out[((size_t)b * NTOK + t1) * CDIM + w * 32 + l31] = po1[r] + pb;
  }
}

extern "C" void kernel_launch(void* const* d_in, const int* in_sizes, int n_in,
                              void* d_out, int out_size, void* d_ws, size_t ws_size,
                              hipStream_t stream) {
  const float* x          = (const float*)d_in[0];
  const float* qkv_w      = (const float*)d_in[1];
  const float* qkv_b      = (const float*)d_in[2];
  const float* proj_w     = (const float*)d_in[3];
  const float* proj_b     = (const float*)d_in[4];
  const float* bias_table = (const float*)d_in[5];
  const int*   rel_idx    = (const int*)d_in[6];

  unsigned short* wq = (unsigned short*)d_ws;          // 768*256 bf16, frag-ordered
  unsigned short* wp = wq + 768 * 256;                 // 256*256 bf16, frag-ordered
  float* biasT = (float*)(wp + 256 * 256);             // 32768 f32, frag-ordered

  prep_kernel<<<768, 256, 0, stream>>>(qkv_w, proj_w, bias_table, rel_idx, wq, wp, biasT);
  mhsa_kernel<<<2048, 512, 0, stream>>>(x, wq, wp, biasT, qkv_b, proj_b, (float*)d_out);
}

// Round 3
// 354.160 us; speedup vs baseline: 2.4632x; 2.4632x over previous
//
#include <hip/hip_runtime.h>
#include <hip/hip_bf16.h>

typedef __attribute__((ext_vector_type(8))) short bf16x8;
typedef __attribute__((ext_vector_type(4))) float f32x4;
typedef __attribute__((ext_vector_type(16))) float f32x16;

#define NTOK 50
#define CDIM 256
#define NH   8
#define SCALE 0.17677669529663687f   // 1/sqrt(32)
#define MFMA32(a,b,c) __builtin_amdgcn_mfma_f32_32x32x16_bf16(a,b,c,0,0,0)
#define Z16 {0.f,0.f,0.f,0.f,0.f,0.f,0.f,0.f,0.f,0.f,0.f,0.f,0.f,0.f,0.f,0.f}

__device__ __forceinline__ unsigned short f2bf(float f) {
  union { __hip_bfloat16 h; unsigned short u; } c;
  c.h = __float2bfloat16(f);  // RNE
  return c.u;
}
__device__ __forceinline__ unsigned pk2(float a, float b) {
  return (unsigned)f2bf(a) | ((unsigned)f2bf(b) << 16);
}

// Exchange primitive (validated r1/r2: absmax 0.0117): packed 32x32 C-tile
// (pk[grp] = regs grp*4+rr over axis value rr+8*grp+4*half) -> MFMA A/B
// fragment for axis chunk c1 (values c1*16 + myh*8 + j). 2 shfl + cndmasks.
__device__ __forceinline__ bf16x8 xchg(uint2 pkA, uint2 pkB, int myh) {
  unsigned ownx = myh ? pkB.x : pkA.x, owny = myh ? pkB.y : pkA.y;
  unsigned crx  = myh ? pkA.x : pkB.x, cry  = myh ? pkA.y : pkB.y;
  crx = (unsigned)__shfl_xor((int)crx, 32);
  cry = (unsigned)__shfl_xor((int)cry, 32);
  union { bf16x8 v; unsigned u[4]; } r;
  r.u[0] = myh ? crx : ownx;
  r.u[1] = myh ? cry : owny;
  r.u[2] = myh ? ownx : crx;
  r.u[3] = myh ? owny : cry;
  return r.v;
}

// Swizzled 32KB tile (validated r2: 0 bank conflicts):
// phys_byte(row, col_byte) = row*512 + ((col_byte>>4) ^ (row&31))*16 + (col_byte&15)
__device__ __forceinline__ bf16x8 ld_tile(const char* base, int row, int kc, int myh) {
  int byte = row * 512 + ((((kc << 1) | myh) ^ (row & 31)) << 4);
  return *(const bf16x8*)(base + byte);
}

// prep: W -> bf16 in FRAGMENT order (coalesced dwordx4 streams in main kernel),
// Q rows pre-scaled; biasT in register-order [h][kt][qt][grp][hh][l31][rr] with
// key-mask folded in.
__global__ void prep_kernel(const float* __restrict__ qkv_w, const float* __restrict__ proj_w,
                            const float* __restrict__ bias_table, const int* __restrict__ rel_idx,
                            unsigned short* __restrict__ wq, unsigned short* __restrict__ wp,
                            float* __restrict__ biasT) {
  int i = blockIdx.x * 256 + (int)threadIdx.x;
  if (i < 768 * 256) {
    int row = i >> 8, col = i & 255;
    int mat = row >> 8, h = (row >> 5) & 7, r31 = row & 31;
    int kc = col >> 4, hh = (col >> 3) & 1, j = col & 7;
    int dst = ((((mat * 8 + h) * 16 + kc) * 2 + hh) * 32 + r31) * 8 + j;
    float v = qkv_w[i];
    if (mat == 0) v *= SCALE;
    wq[dst] = f2bf(v);
  }
  if (i < 256 * 256) {
    int row = i >> 8, col = i & 255;
    int wv = row >> 5, r31 = row & 31;
    int kc = col >> 4, hh = (col >> 3) & 1, j = col & 7;
    int dst = (((wv * 16 + kc) * 2 + hh) * 32 + r31) * 8 + j;
    wp[dst] = f2bf(proj_w[i]);
  }
  if (i < 32768) {
    int h = i >> 12, kt = (i >> 11) & 1, qt = (i >> 10) & 1;
    int grp = (i >> 8) & 3, hh = (i >> 7) & 1, l31 = (i >> 2) & 31, rr = i & 3;
    int key = kt * 32 + grp * 8 + hh * 4 + rr;
    int query = qt * 32 + l31;
    float v;
    if (key >= NTOK) v = -1e30f;                               // padded keys: softmax mask
    else if (query == 0 || key == 0 || query >= NTOK) v = 0.f; // region token row/col
    else v = bias_table[rel_idx[(query - 1) * 49 + (key - 1)] * NH + h];
    biasT[i] = v;
  }
}

__global__ __launch_bounds__(256, 3)
void mhsa_kernel(const float* __restrict__ x, const unsigned short* __restrict__ wq,
                 const unsigned short* __restrict__ wp, const float* __restrict__ biasT,
                 const float* __restrict__ qkv_b, const float* __restrict__ proj_b,
                 float* __restrict__ out) {
  __shared__ uint4 shbuf[2048];            // 32 KB: x tile, later aliased as O tile
  char* base = (char*)shbuf;

  const int b = blockIdx.x;
  const int tid = (int)threadIdx.x;
  const int w = tid >> 6;                  // wave id 0..3; handles heads w and w+4
  const int lane = tid & 63;
  const int l31 = lane & 31;
  const int myh = lane >> 5;

  // ---- stage x -> swizzled bf16 LDS tile (rows >= 50 zeroed) ----
  {
    const float* xb = x + (size_t)b * NTOK * CDIM;
    #pragma unroll
    for (int i = 0; i < 16; ++i) {
      int flat = i * 256 + tid;
      int row = flat >> 6, c4 = flat & 63;
      uint2 pv = make_uint2(0u, 0u);
      if (row < NTOK) {
        float4 v = *(const float4*)&xb[row * CDIM + c4 * 4];
        pv.x = pk2(v.x, v.y);
        pv.y = pk2(v.z, v.w);
      }
      int byte = row * 512 + ((((c4 >> 1) ^ (row & 31)) << 4) | ((c4 & 1) << 3));
      *(uint2*)(base + byte) = pv;
    }
  }
  __syncthreads();

  uint2 Opk[2][2][4];   // [pass][qt][grp] packed bf16 O-tiles: 32 VGPRs total

  #pragma unroll
  for (int pass = 0; pass < 2; ++pass) {
    const int h = w + 4 * pass;
    const unsigned short* wQb = wq + (size_t)h * 8192;
    const unsigned short* wKb = wq + 65536 + (size_t)h * 8192;
    const unsigned short* wVb = wq + 131072 + (size_t)h * 8192;

    // ---- fused Q+K GEMM (shared x fragments), A = W (frag-ordered), B = x^T ----
    bf16x8 Qf[2][2], Kf[2][2];
    {
      f32x16 accQ0 = Z16, accQ1 = Z16, accK0 = Z16, accK1 = Z16;
      #pragma unroll
      for (int kc = 0; kc < 16; ++kc) {
        bf16x8 wqf = *(const bf16x8*)&wQb[(kc * 2 + myh) * 256 + l31 * 8];
        bf16x8 wkf = *(const bf16x8*)&wKb[(kc * 2 + myh) * 256 + l31 * 8];
        bf16x8 x0 = ld_tile(base, l31, kc, myh);
        bf16x8 x1 = ld_tile(base, 32 + l31, kc, myh);
        accQ0 = MFMA32(wqf, x0, accQ0);
        accK0 = MFMA32(wkf, x0, accK0);
        accQ1 = MFMA32(wqf, x1, accQ1);
        accK1 = MFMA32(wkf, x1, accK1);
      }
      #pragma unroll
      for (int r = 0; r < 16; ++r) {
        int f = (r & 3) + 8 * (r >> 2) + 4 * myh;
        float bq = qkv_b[h * 32 + f] * SCALE;
        float bk = qkv_b[CDIM + h * 32 + f];
        accQ0[r] += bq; accQ1[r] += bq;
        accK0[r] += bk; accK1[r] += bk;
      }
      uint2 pq[4], pk[4];
      #pragma unroll
      for (int gI = 0; gI < 4; ++gI) {
        pq[gI] = make_uint2(pk2(accQ0[4*gI], accQ0[4*gI+1]), pk2(accQ0[4*gI+2], accQ0[4*gI+3]));
        pk[gI] = make_uint2(pk2(accK0[4*gI], accK0[4*gI+1]), pk2(accK0[4*gI+2], accK0[4*gI+3]));
      }
      Qf[0][0] = xchg(pq[0], pq[1], myh);  Qf[0][1] = xchg(pq[2], pq[3], myh);
      Kf[0][0] = xchg(pk[0], pk[1], myh);  Kf[0][1] = xchg(pk[2], pk[3], myh);
      #pragma unroll
      for (int gI = 0; gI < 4; ++gI) {
        pq[gI] = make_uint2(pk2(accQ1[4*gI], accQ1[4*gI+1]), pk2(accQ1[4*gI+2], accQ1[4*gI+3]));
        pk[gI] = make_uint2(pk2(accK1[4*gI], accK1[4*gI+1]), pk2(accK1[4*gI+2], accK1[4*gI+3]));
      }
      Qf[1][0] = xchg(pq[0], pq[1], myh);  Qf[1][1] = xchg(pq[2], pq[3], myh);
      Kf[1][0] = xchg(pk[0], pk[1], myh);  Kf[1][1] = xchg(pk[2], pk[3], myh);
    }

    // ---- V GEMM: A = x (rows=tokens), B = Wv^T (cols=d) ----
    bf16x8 Vf[4];
    {
      f32x16 accV0 = Z16, accV1 = Z16;
      #pragma unroll
      for (int kc = 0; kc < 16; ++kc) {
        bf16x8 wvf = *(const bf16x8*)&wVb[(kc * 2 + myh) * 256 + l31 * 8];
        accV0 = MFMA32(ld_tile(base, l31, kc, myh), wvf, accV0);
        accV1 = MFMA32(ld_tile(base, 32 + l31, kc, myh), wvf, accV1);
      }
      float bv = qkv_b[2 * CDIM + h * 32 + l31];
      #pragma unroll
      for (int r = 0; r < 16; ++r) { accV0[r] += bv; accV1[r] += bv; }
      uint2 pv0[4], pv1[4];
      #pragma unroll
      for (int gI = 0; gI < 4; ++gI) {
        pv0[gI] = make_uint2(pk2(accV0[4*gI], accV0[4*gI+1]), pk2(accV0[4*gI+2], accV0[4*gI+3]));
        pv1[gI] = make_uint2(pk2(accV1[4*gI], accV1[4*gI+1]), pk2(accV1[4*gI+2], accV1[4*gI+3]));
      }
      Vf[0] = xchg(pv0[0], pv0[1], myh);  Vf[1] = xchg(pv0[2], pv0[3], myh);
      Vf[2] = xchg(pv1[0], pv1[1], myh);  Vf[3] = xchg(pv1[2], pv1[3], myh);
    }

    // ---- per query-tile: S^T = K*Q^T (+bias) -> softmax (lane-local) -> P -> O = P*V ----
    #pragma unroll
    for (int qt = 0; qt < 2; ++qt) {
      f32x16 s0 = Z16, s1 = Z16;
      s0 = MFMA32(Kf[0][0], Qf[qt][0], s0);  s0 = MFMA32(Kf[0][1], Qf[qt][1], s0);
      s1 = MFMA32(Kf[1][0], Qf[qt][0], s1);  s1 = MFMA32(Kf[1][1], Qf[qt][1], s1);
      // bias add (frag-ordered, coalesced dwordx4)
      #pragma unroll
      for (int kt = 0; kt < 2; ++kt) {
        const float* bT = biasT + (size_t)(((h * 2 + kt) * 2 + qt) * 1024);
        #pragma unroll
        for (int gI = 0; gI < 4; ++gI) {
          f32x4 bv = *(const f32x4*)&bT[(gI * 2 + myh) * 128 + l31 * 4];
          if (kt == 0) { s0[4*gI] += bv[0]; s0[4*gI+1] += bv[1]; s0[4*gI+2] += bv[2]; s0[4*gI+3] += bv[3]; }
          else         { s1[4*gI] += bv[0]; s1[4*gI+1] += bv[1]; s1[4*gI+2] += bv[2]; s1[4*gI+3] += bv[3]; }
        }
      }
      // softmax over 64 keys: 32 lane-local + one cross-half shfl
      float mx = -3e38f;
      #pragma unroll
      for (int r = 0; r < 16; ++r) { mx = fmaxf(mx, s0[r]); mx = fmaxf(mx, s1[r]); }
      mx = fmaxf(mx, __shfl_xor(mx, 32));
      float sum = 0.f;
      #pragma unroll
      for (int r = 0; r < 16; ++r) {
        float e0 = __expf(s0[r] - mx); s0[r] = e0; sum += e0;
        float e1 = __expf(s1[r] - mx); s1[r] = e1; sum += e1;
      }
      sum += __shfl_xor(sum, 32);
      float inv = 1.f / sum;
      uint2 pp0[4], pp1[4];
      #pragma unroll
      for (int gI = 0; gI < 4; ++gI) {
        pp0[gI] = make_uint2(pk2(s0[4*gI]*inv, s0[4*gI+1]*inv), pk2(s0[4*gI+2]*inv, s0[4*gI+3]*inv));
        pp1[gI] = make_uint2(pk2(s1[4*gI]*inv, s1[4*gI+1]*inv), pk2(s1[4*gI+2]*inv, s1[4*gI+3]*inv));
      }
      bf16x8 Pf0 = xchg(pp0[0], pp0[1], myh), Pf1 = xchg(pp0[2], pp0[3], myh);
      bf16x8 Pf2 = xchg(pp1[0], pp1[1], myh), Pf3 = xchg(pp1[2], pp1[3], myh);
      f32x16 o = Z16;
      o = MFMA32(Pf0, Vf[0], o);
      o = MFMA32(Pf1, Vf[1], o);
      o = MFMA32(Pf2, Vf[2], o);
      o = MFMA32(Pf3, Vf[3], o);
      // pack O to bf16 immediately -> 8 regs per qt-tile, all f32 accs released
      #pragma unroll
      for (int gI = 0; gI < 4; ++gI)
        Opk[pass][qt][gI] = make_uint2(pk2(o[4*gI], o[4*gI+1]), pk2(o[4*gI+2], o[4*gI+3]));
    }
  }

  __syncthreads();   // all waves done reading x -> safe to overwrite with O
  // ---- O -> swizzled LDS tile (cols h*32 + l31), bf16 ----
  #pragma unroll
  for (int pass = 0; pass < 2; ++pass) {
    const int h = w + 4 * pass;
    const int slotbase = (h << 2) | (l31 >> 3);
    #pragma unroll
    for (int qt = 0; qt < 2; ++qt)
      #pragma unroll
      for (int gI = 0; gI < 4; ++gI) {
        const unsigned xv = Opk[pass][qt][gI].x, yv = Opk[pass][qt][gI].y;
        #pragma unroll
        for (int rr = 0; rr < 4; ++rr) {
          unsigned short val = (unsigned short)(((rr < 2 ? xv : yv) >> ((rr & 1) * 16)) & 0xffffu);
          int t = qt * 32 + rr + 8 * gI + 4 * myh;
          int byte = t * 512 + (((slotbase ^ (t & 31)) << 4) | ((l31 & 7) << 1));
          *(unsigned short*)(base + byte) = val;
        }
      }
  }
  __syncthreads();

  // ---- proj: out = O * Wp^T + pb; wave covers e-col groups w and w+4 ----
  #pragma unroll
  for (int ep = 0; ep < 2; ++ep) {
    const int eg = ep * 4 + w;
    const unsigned short* wPb = wp + (size_t)eg * 8192;
    f32x16 po0 = Z16, po1 = Z16;
    #pragma unroll
    for (int kc = 0; kc < 16; ++kc) {
      bf16x8 wpf = *(const bf16x8*)&wPb[(kc * 2 + myh) * 256 + l31 * 8];
      po0 = MFMA32(ld_tile(base, l31, kc, myh), wpf, po0);
      po1 = MFMA32(ld_tile(base, 32 + l31, kc, myh), wpf, po1);
    }
    const float pb = proj_b[eg * 32 + l31];
    #pragma unroll
    for (int r = 0; r < 16; ++r) {
      int t0 = (r & 3) + 8 * (r >> 2) + 4 * myh;
      if (t0 < NTOK) out[((size_t)b * NTOK + t0) * CDIM + eg * 32 + l31] = po0[r] + pb;
      int t1 = 32 + t0;
      if (t1 < NTOK) out[((size_t)b * NTOK + t1) * CDIM + eg * 32 + l31] = po1[r] + pb;
    }
  }
}

extern "C" void kernel_launch(void* const* d_in, const int* in_sizes, int n_in,
                              void* d_out, int out_size, void* d_ws, size_t ws_size,
                              hipStream_t stream) {
  const float* x          = (const float*)d_in[0];
  const float* qkv_w      = (const float*)d_in[1];
  const float* qkv_b      = (const float*)d_in[2];
  const float* proj_w     = (const float*)d_in[3];
  const float* proj_b     = (const float*)d_in[4];
  const float* bias_table = (const float*)d_in[5];
  const int*   rel_idx    = (const int*)d_in[6];

  unsigned short* wq = (unsigned short*)d_ws;          // 768*256 bf16, frag-ordered
  unsigned short* wp = wq + 768 * 256;                 // 256*256 bf16, frag-ordered
  float* biasT = (float*)(wp + 256 * 256);             // 32768 f32, frag-ordered

  prep_kernel<<<768, 256, 0, stream>>>(qkv_w, proj_w, bias_table, rel_idx, wq, wp, biasT);
  mhsa_kernel<<<2048, 256, 0, stream>>>(x, wq, wp, biasT, qkv_b, proj_b, (float*)d_out);
}

// Round 4
// 184.011 us; speedup vs baseline: 4.7408x; 1.9247x over previous
//
#include <hip/hip_runtime.h>
#include <hip/hip_bf16.h>

typedef __attribute__((ext_vector_type(8))) short bf16x8;
typedef __attribute__((ext_vector_type(4))) float f32x4;
typedef __attribute__((ext_vector_type(16))) float f32x16;

#define NTOK 50
#define CDIM 256
#define NH   8
#define SCALE 0.17677669529663687f   // 1/sqrt(32)
#define MFMA32(a,b,c) __builtin_amdgcn_mfma_f32_32x32x16_bf16(a,b,c,0,0,0)
#define Z16 {0.f,0.f,0.f,0.f,0.f,0.f,0.f,0.f,0.f,0.f,0.f,0.f,0.f,0.f,0.f,0.f}

__device__ __forceinline__ unsigned short f2bf(float f) {
  union { __hip_bfloat16 h; unsigned short u; } c;
  c.h = __float2bfloat16(f);  // RNE
  return c.u;
}
__device__ __forceinline__ unsigned pk2(float a, float b) {
  return (unsigned)f2bf(a) | ((unsigned)f2bf(b) << 16);
}

// Exchange primitive (validated r1-r3: absmax 0.0117): packed 32x32 C-tile
// (pk[grp] = regs grp*4+rr over axis value rr+8*grp+4*half) -> MFMA A/B
// fragment for axis chunk c1 (values c1*16 + myh*8 + j). 2 shfl + cndmasks.
__device__ __forceinline__ bf16x8 xchg(uint2 pkA, uint2 pkB, int myh) {
  unsigned ownx = myh ? pkB.x : pkA.x, owny = myh ? pkB.y : pkA.y;
  unsigned crx  = myh ? pkA.x : pkB.x, cry  = myh ? pkA.y : pkB.y;
  crx = (unsigned)__shfl_xor((int)crx, 32);
  cry = (unsigned)__shfl_xor((int)cry, 32);
  union { bf16x8 v; unsigned u[4]; } r;
  r.u[0] = myh ? crx : ownx;
  r.u[1] = myh ? cry : owny;
  r.u[2] = myh ? ownx : crx;
  r.u[3] = myh ? owny : cry;
  return r.v;
}

// Swizzled 32KB tile (validated r2/r3: 0 bank conflicts):
// phys_byte(row, col_byte) = row*512 + ((col_byte>>4) ^ (row&31))*16 + (col_byte&15)
__device__ __forceinline__ bf16x8 ld_tile(const char* base, int row, int kc, int myh) {
  int byte = row * 512 + ((((kc << 1) | myh) ^ (row & 31)) << 4);
  return *(const bf16x8*)(base + byte);
}

// prep: W -> bf16 in FRAGMENT order (coalesced dwordx4 streams in main kernel),
// Q rows pre-scaled; biasT in register-order [h][kt][qt][grp][hh][l31][rr] with
// key-mask folded in.
__global__ void prep_kernel(const float* __restrict__ qkv_w, const float* __restrict__ proj_w,
                            const float* __restrict__ bias_table, const int* __restrict__ rel_idx,
                            unsigned short* __restrict__ wq, unsigned short* __restrict__ wp,
                            float* __restrict__ biasT) {
  int i = blockIdx.x * 256 + (int)threadIdx.x;
  if (i < 768 * 256) {
    int row = i >> 8, col = i & 255;
    int mat = row >> 8, h = (row >> 5) & 7, r31 = row & 31;
    int kc = col >> 4, hh = (col >> 3) & 1, j = col & 7;
    int dst = ((((mat * 8 + h) * 16 + kc) * 2 + hh) * 32 + r31) * 8 + j;
    float v = qkv_w[i];
    if (mat == 0) v *= SCALE;
    wq[dst] = f2bf(v);
  }
  if (i < 256 * 256) {
    int row = i >> 8, col = i & 255;
    int wv = row >> 5, r31 = row & 31;
    int kc = col >> 4, hh = (col >> 3) & 1, j = col & 7;
    int dst = (((wv * 16 + kc) * 2 + hh) * 32 + r31) * 8 + j;
    wp[dst] = f2bf(proj_w[i]);
  }
  if (i < 32768) {
    int h = i >> 12, kt = (i >> 11) & 1, qt = (i >> 10) & 1;
    int grp = (i >> 8) & 3, hh = (i >> 7) & 1, l31 = (i >> 2) & 31, rr = i & 3;
    int key = kt * 32 + grp * 8 + hh * 4 + rr;
    int query = qt * 32 + l31;
    float v;
    if (key >= NTOK) v = -1e30f;                               // padded keys: softmax mask
    else if (query == 0 || key == 0 || query >= NTOK) v = 0.f; // region token row/col
    else v = bias_table[rel_idx[(query - 1) * 49 + (key - 1)] * NH + h];
    biasT[i] = v;
  }
}

// 512 threads, wave = head. __launch_bounds__(512,2): 256-reg unified cap ->
// no spill (r3's 1.0 GB scratch traffic came from the 170-cap split 84v/86a).
__global__ __launch_bounds__(512, 2)
void mhsa_kernel(const float* __restrict__ x, const unsigned short* __restrict__ wq,
                 const unsigned short* __restrict__ wp, const float* __restrict__ biasT,
                 const float* __restrict__ qkv_b, const float* __restrict__ proj_b,
                 float* __restrict__ out) {
  __shared__ uint4 shbuf[2048];            // 32 KB: x tile, later aliased as O tile
  char* base = (char*)shbuf;

  const int b = blockIdx.x;
  const int tid = (int)threadIdx.x;
  const int w = tid >> 6;                  // wave id = head
  const int lane = tid & 63;
  const int l31 = lane & 31;
  const int myh = lane >> 5;

  // ---- stage x -> swizzled bf16 LDS tile (rows >= 50 zeroed) ----
  {
    const float* xb = x + (size_t)b * NTOK * CDIM;
    #pragma unroll
    for (int i = 0; i < 8; ++i) {
      int flat = i * 512 + tid;
      int row = flat >> 6, c4 = flat & 63;
      uint2 pv = make_uint2(0u, 0u);
      if (row < NTOK) {
        float4 v = *(const float4*)&xb[row * CDIM + c4 * 4];
        pv.x = pk2(v.x, v.y);
        pv.y = pk2(v.z, v.w);
      }
      int byte = row * 512 + ((((c4 >> 1) ^ (row & 31)) << 4) | ((c4 & 1) << 3));
      *(uint2*)(base + byte) = pv;
    }
  }
  __syncthreads();

  const unsigned short* wQb = wq + (size_t)w * 8192;
  const unsigned short* wKb = wq + 65536 + (size_t)w * 8192;
  const unsigned short* wVb = wq + 131072 + (size_t)w * 8192;

  // ---- fused Q+K GEMM (shared x fragments), A = W (frag-ordered), B = x^T ----
  bf16x8 Qf[2][2], Kf[2][2];
  {
    f32x16 accQ0 = Z16, accQ1 = Z16, accK0 = Z16, accK1 = Z16;
    #pragma unroll
    for (int kc = 0; kc < 16; ++kc) {
      bf16x8 wqf = *(const bf16x8*)&wQb[(kc * 2 + myh) * 256 + l31 * 8];
      bf16x8 wkf = *(const bf16x8*)&wKb[(kc * 2 + myh) * 256 + l31 * 8];
      bf16x8 x0 = ld_tile(base, l31, kc, myh);
      bf16x8 x1 = ld_tile(base, 32 + l31, kc, myh);
      accQ0 = MFMA32(wqf, x0, accQ0);
      accK0 = MFMA32(wkf, x0, accK0);
      accQ1 = MFMA32(wqf, x1, accQ1);
      accK1 = MFMA32(wkf, x1, accK1);
    }
    #pragma unroll
    for (int r = 0; r < 16; ++r) {
      int f = (r & 3) + 8 * (r >> 2) + 4 * myh;
      float bq = qkv_b[w * 32 + f] * SCALE;
      float bk = qkv_b[CDIM + w * 32 + f];
      accQ0[r] += bq; accQ1[r] += bq;
      accK0[r] += bk; accK1[r] += bk;
    }
    uint2 pq[4], pk[4];
    #pragma unroll
    for (int gI = 0; gI < 4; ++gI) {
      pq[gI] = make_uint2(pk2(accQ0[4*gI], accQ0[4*gI+1]), pk2(accQ0[4*gI+2], accQ0[4*gI+3]));
      pk[gI] = make_uint2(pk2(accK0[4*gI], accK0[4*gI+1]), pk2(accK0[4*gI+2], accK0[4*gI+3]));
    }
    Qf[0][0] = xchg(pq[0], pq[1], myh);  Qf[0][1] = xchg(pq[2], pq[3], myh);
    Kf[0][0] = xchg(pk[0], pk[1], myh);  Kf[0][1] = xchg(pk[2], pk[3], myh);
    #pragma unroll
    for (int gI = 0; gI < 4; ++gI) {
      pq[gI] = make_uint2(pk2(accQ1[4*gI], accQ1[4*gI+1]), pk2(accQ1[4*gI+2], accQ1[4*gI+3]));
      pk[gI] = make_uint2(pk2(accK1[4*gI], accK1[4*gI+1]), pk2(accK1[4*gI+2], accK1[4*gI+3]));
    }
    Qf[1][0] = xchg(pq[0], pq[1], myh);  Qf[1][1] = xchg(pq[2], pq[3], myh);
    Kf[1][0] = xchg(pk[0], pk[1], myh);  Kf[1][1] = xchg(pk[2], pk[3], myh);
  }

  // ---- V GEMM: A = x (rows=tokens), B = Wv^T (cols=d) ----
  bf16x8 Vf[4];
  {
    f32x16 accV0 = Z16, accV1 = Z16;
    #pragma unroll
    for (int kc = 0; kc < 16; ++kc) {
      bf16x8 wvf = *(const bf16x8*)&wVb[(kc * 2 + myh) * 256 + l31 * 8];
      accV0 = MFMA32(ld_tile(base, l31, kc, myh), wvf, accV0);
      accV1 = MFMA32(ld_tile(base, 32 + l31, kc, myh), wvf, accV1);
    }
    float bv = qkv_b[2 * CDIM + w * 32 + l31];
    #pragma unroll
    for (int r = 0; r < 16; ++r) { accV0[r] += bv; accV1[r] += bv; }
    uint2 pv0[4], pv1[4];
    #pragma unroll
    for (int gI = 0; gI < 4; ++gI) {
      pv0[gI] = make_uint2(pk2(accV0[4*gI], accV0[4*gI+1]), pk2(accV0[4*gI+2], accV0[4*gI+3]));
      pv1[gI] = make_uint2(pk2(accV1[4*gI], accV1[4*gI+1]), pk2(accV1[4*gI+2], accV1[4*gI+3]));
    }
    Vf[0] = xchg(pv0[0], pv0[1], myh);  Vf[1] = xchg(pv0[2], pv0[3], myh);
    Vf[2] = xchg(pv1[0], pv1[1], myh);  Vf[3] = xchg(pv1[2], pv1[3], myh);
  }

  // ---- per query-tile: S^T = K*Q^T (+bias) -> softmax (lane-local) -> P -> O = P*V ----
  uint2 Opk[2][4];   // packed bf16 O-tiles, 16 VGPRs
  #pragma unroll
  for (int qt = 0; qt < 2; ++qt) {
    f32x16 s0 = Z16, s1 = Z16;
    s0 = MFMA32(Kf[0][0], Qf[qt][0], s0);  s0 = MFMA32(Kf[0][1], Qf[qt][1], s0);
    s1 = MFMA32(Kf[1][0], Qf[qt][0], s1);  s1 = MFMA32(Kf[1][1], Qf[qt][1], s1);
    // bias add (frag-ordered, coalesced dwordx4)
    #pragma unroll
    for (int kt = 0; kt < 2; ++kt) {
      const float* bT = biasT + (size_t)(((w * 2 + kt) * 2 + qt) * 1024);
      #pragma unroll
      for (int gI = 0; gI < 4; ++gI) {
        f32x4 bv = *(const f32x4*)&bT[(gI * 2 + myh) * 128 + l31 * 4];
        if (kt == 0) { s0[4*gI] += bv[0]; s0[4*gI+1] += bv[1]; s0[4*gI+2] += bv[2]; s0[4*gI+3] += bv[3]; }
        else         { s1[4*gI] += bv[0]; s1[4*gI+1] += bv[1]; s1[4*gI+2] += bv[2]; s1[4*gI+3] += bv[3]; }
      }
    }
    // softmax over 64 keys: 32 lane-local + one cross-half shfl
    float mx = -3e38f;
    #pragma unroll
    for (int r = 0; r < 16; ++r) { mx = fmaxf(mx, s0[r]); mx = fmaxf(mx, s1[r]); }
    mx = fmaxf(mx, __shfl_xor(mx, 32));
    float sum = 0.f;
    #pragma unroll
    for (int r = 0; r < 16; ++r) {
      float e0 = __expf(s0[r] - mx); s0[r] = e0; sum += e0;
      float e1 = __expf(s1[r] - mx); s1[r] = e1; sum += e1;
    }
    sum += __shfl_xor(sum, 32);
    float inv = 1.f / sum;
    uint2 pp0[4], pp1[4];
    #pragma unroll
    for (int gI = 0; gI < 4; ++gI) {
      pp0[gI] = make_uint2(pk2(s0[4*gI]*inv, s0[4*gI+1]*inv), pk2(s0[4*gI+2]*inv, s0[4*gI+3]*inv));
      pp1[gI] = make_uint2(pk2(s1[4*gI]*inv, s1[4*gI+1]*inv), pk2(s1[4*gI+2]*inv, s1[4*gI+3]*inv));
    }
    bf16x8 Pf0 = xchg(pp0[0], pp0[1], myh), Pf1 = xchg(pp0[2], pp0[3], myh);
    bf16x8 Pf2 = xchg(pp1[0], pp1[1], myh), Pf3 = xchg(pp1[2], pp1[3], myh);
    f32x16 o = Z16;
    o = MFMA32(Pf0, Vf[0], o);
    o = MFMA32(Pf1, Vf[1], o);
    o = MFMA32(Pf2, Vf[2], o);
    o = MFMA32(Pf3, Vf[3], o);
    // pack O to bf16 immediately: releases all f32 accumulators
    #pragma unroll
    for (int gI = 0; gI < 4; ++gI)
      Opk[qt][gI] = make_uint2(pk2(o[4*gI], o[4*gI+1]), pk2(o[4*gI+2], o[4*gI+3]));
  }

  __syncthreads();   // all waves done reading x -> safe to overwrite with O
  // ---- O -> swizzled LDS tile (cols w*32 + l31), bf16 ----
  {
    const int slotbase = (w << 2) | (l31 >> 3);
    #pragma unroll
    for (int qt = 0; qt < 2; ++qt)
      #pragma unroll
      for (int gI = 0; gI < 4; ++gI) {
        const unsigned xv = Opk[qt][gI].x, yv = Opk[qt][gI].y;
        #pragma unroll
        for (int rr = 0; rr < 4; ++rr) {
          unsigned short val = (unsigned short)(((rr < 2 ? xv : yv) >> ((rr & 1) * 16)) & 0xffffu);
          int t = qt * 32 + rr + 8 * gI + 4 * myh;
          int byte = t * 512 + (((slotbase ^ (t & 31)) << 4) | ((l31 & 7) << 1));
          *(unsigned short*)(base + byte) = val;
        }
      }
  }
  __syncthreads();

  // ---- proj: out = O * Wp^T + pb; wave owns e-cols [32w, 32w+32) ----
  const unsigned short* wPb = wp + (size_t)w * 8192;
  f32x16 po0 = Z16, po1 = Z16;
  #pragma unroll
  for (int kc = 0; kc < 16; ++kc) {
    bf16x8 wpf = *(const bf16x8*)&wPb[(kc * 2 + myh) * 256 + l31 * 8];
    po0 = MFMA32(ld_tile(base, l31, kc, myh), wpf, po0);
    po1 = MFMA32(ld_tile(base, 32 + l31, kc, myh), wpf, po1);
  }
  const float pb = proj_b[w * 32 + l31];
  #pragma unroll
  for (int r = 0; r < 16; ++r) {
    int t0 = (r & 3) + 8 * (r >> 2) + 4 * myh;
    if (t0 < NTOK) out[((size_t)b * NTOK + t0) * CDIM + w * 32 + l31] = po0[r] + pb;
    int t1 = 32 + t0;
    if (t1 < NTOK) out[((size_t)b * NTOK + t1) * CDIM + w * 32 + l31] = po1[r] + pb;
  }
}

extern "C" void kernel_launch(void* const* d_in, const int* in_sizes, int n_in,
                              void* d_out, int out_size, void* d_ws, size_t ws_size,
                              hipStream_t stream) {
  const float* x          = (const float*)d_in[0];
  const float* qkv_w      = (const float*)d_in[1];
  const float* qkv_b      = (const float*)d_in[2];
  const float* proj_w     = (const float*)d_in[3];
  const float* proj_b     = (const float*)d_in[4];
  const float* bias_table = (const float*)d_in[5];
  const int*   rel_idx    = (const int*)d_in[6];

  unsigned short* wq = (unsigned short*)d_ws;          // 768*256 bf16, frag-ordered
  unsigned short* wp = wq + 768 * 256;                 // 256*256 bf16, frag-ordered
  float* biasT = (float*)(wp + 256 * 256);             // 32768 f32, frag-ordered

  prep_kernel<<<768, 256, 0, stream>>>(qkv_w, proj_w, bias_table, rel_idx, wq, wp, biasT);
  mhsa_kernel<<<2048, 512, 0, stream>>>(x, wq, wp, biasT, qkv_b, proj_b, (float*)d_out);
}

// Round 5
// 175.740 us; speedup vs baseline: 4.9640x; 1.0471x over previous
//
#include <hip/hip_runtime.h>
#include <hip/hip_bf16.h>

typedef __attribute__((ext_vector_type(8))) short bf16x8;
typedef __attribute__((ext_vector_type(4))) float f32x4;
typedef __attribute__((ext_vector_type(16))) float f32x16;

#define NTOK 50
#define CDIM 256
#define NH   8
#define SCALE 0.17677669529663687f   // 1/sqrt(32)
#define MFMA32(a,b,c) __builtin_amdgcn_mfma_f32_32x32x16_bf16(a,b,c,0,0,0)
#define Z16 {0.f,0.f,0.f,0.f,0.f,0.f,0.f,0.f,0.f,0.f,0.f,0.f,0.f,0.f,0.f,0.f}

__device__ __forceinline__ unsigned short f2bf(float f) {
  union { __hip_bfloat16 h; unsigned short u; } c;
  c.h = __float2bfloat16(f);  // RNE
  return c.u;
}
__device__ __forceinline__ unsigned pk2(float a, float b) {
  return (unsigned)f2bf(a) | ((unsigned)f2bf(b) << 16);
}

// Exchange primitive (validated r1-r4: absmax 0.0117): packed 32x32 C-tile
// (pk[grp] = regs grp*4+rr over axis value rr+8*grp+4*half) -> MFMA A/B
// fragment for axis chunk c1 (values c1*16 + myh*8 + j). 2 shfl + cndmasks.
__device__ __forceinline__ bf16x8 xchg(uint2 pkA, uint2 pkB, int myh) {
  unsigned ownx = myh ? pkB.x : pkA.x, owny = myh ? pkB.y : pkA.y;
  unsigned crx  = myh ? pkA.x : pkB.x, cry  = myh ? pkA.y : pkB.y;
  crx = (unsigned)__shfl_xor((int)crx, 32);
  cry = (unsigned)__shfl_xor((int)cry, 32);
  union { bf16x8 v; unsigned u[4]; } r;
  r.u[0] = myh ? crx : ownx;
  r.u[1] = myh ? cry : owny;
  r.u[2] = myh ? ownx : crx;
  r.u[3] = myh ? owny : cry;
  return r.v;
}

// Swizzled 32KB tile (validated r2-r4: 0 bank conflicts):
// phys_byte(row, col_byte) = row*512 + ((col_byte>>4) ^ (row&31))*16 + (col_byte&15)
__device__ __forceinline__ bf16x8 ld_tile(const char* base, int row, int kc, int myh) {
  int byte = row * 512 + ((((kc << 1) | myh) ^ (row & 31)) << 4);
  return *(const bf16x8*)(base + byte);
}

// prep: W -> bf16 in FRAGMENT order (coalesced dwordx4 streams in main kernel),
// Q rows pre-scaled; biasT in register-order [h][kt][qt][grp][hh][l31][rr] with
// key-mask folded in.
__global__ void prep_kernel(const float* __restrict__ qkv_w, const float* __restrict__ proj_w,
                            const float* __restrict__ bias_table, const int* __restrict__ rel_idx,
                            unsigned short* __restrict__ wq, unsigned short* __restrict__ wp,
                            float* __restrict__ biasT) {
  int i = blockIdx.x * 256 + (int)threadIdx.x;
  if (i < 768 * 256) {
    int row = i >> 8, col = i & 255;
    int mat = row >> 8, h = (row >> 5) & 7, r31 = row & 31;
    int kc = col >> 4, hh = (col >> 3) & 1, j = col & 7;
    int dst = ((((mat * 8 + h) * 16 + kc) * 2 + hh) * 32 + r31) * 8 + j;
    float v = qkv_w[i];
    if (mat == 0) v *= SCALE;
    wq[dst] = f2bf(v);
  }
  if (i < 256 * 256) {
    int row = i >> 8, col = i & 255;
    int wv = row >> 5, r31 = row & 31;
    int kc = col >> 4, hh = (col >> 3) & 1, j = col & 7;
    int dst = (((wv * 16 + kc) * 2 + hh) * 32 + r31) * 8 + j;
    wp[dst] = f2bf(proj_w[i]);
  }
  if (i < 32768) {
    int h = i >> 12, kt = (i >> 11) & 1, qt = (i >> 10) & 1;
    int grp = (i >> 8) & 3, hh = (i >> 7) & 1, l31 = (i >> 2) & 31, rr = i & 3;
    int key = kt * 32 + grp * 8 + hh * 4 + rr;
    int query = qt * 32 + l31;
    float v;
    if (key >= NTOK) v = -1e30f;                               // padded keys: softmax mask
    else if (query == 0 || key == 0 || query >= NTOK) v = 0.f; // region token row/col
    else v = bias_table[rel_idx[(query - 1) * 49 + (key - 1)] * NH + h];
    biasT[i] = v;
  }
}

// 512 threads, wave = head, launch_bounds(512,2) (256-reg cap, validated no-spill r4).
// r5 change: aggressive load-issue scheduling -- pre-barrier weight prefetch +
// distance-2 rotating prefetch in all GEMM loops + cross-phase pre-issue.
__global__ __launch_bounds__(512, 2)
void mhsa_kernel(const float* __restrict__ x, const unsigned short* __restrict__ wq,
                 const unsigned short* __restrict__ wp, const float* __restrict__ biasT,
                 const float* __restrict__ qkv_b, const float* __restrict__ proj_b,
                 float* __restrict__ out) {
  __shared__ uint4 shbuf[2048];            // 32 KB: x tile, later aliased as O tile
  char* base = (char*)shbuf;

  const int b = blockIdx.x;
  const int tid = (int)threadIdx.x;
  const int w = tid >> 6;                  // wave id = head
  const int lane = tid & 63;
  const int l31 = lane & 31;
  const int myh = lane >> 5;

  const unsigned short* wQb = wq + (size_t)w * 8192;
  const unsigned short* wKb = wq + 65536 + (size_t)w * 8192;
  const unsigned short* wVb = wq + 131072 + (size_t)w * 8192;
  const unsigned short* wPb = wp + (size_t)w * 8192;
  const int fragoff = myh * 256 + l31 * 8;   // frag byte-offset pattern within kc

  // ---- pre-issue Q/K weight frags kc=0,1: complete under staging + barrier drain ----
  bf16x8 wqf[2], wkf[2];
  wqf[0] = *(const bf16x8*)&wQb[0 * 512 + fragoff];
  wkf[0] = *(const bf16x8*)&wKb[0 * 512 + fragoff];
  wqf[1] = *(const bf16x8*)&wQb[1 * 512 + fragoff];
  wkf[1] = *(const bf16x8*)&wKb[1 * 512 + fragoff];

  // ---- stage x -> swizzled bf16 LDS tile (rows >= 50 zeroed) ----
  {
    const float* xb = x + (size_t)b * NTOK * CDIM;
    #pragma unroll
    for (int i = 0; i < 8; ++i) {
      int flat = i * 512 + tid;
      int row = flat >> 6, c4 = flat & 63;
      uint2 pv = make_uint2(0u, 0u);
      if (row < NTOK) {
        float4 v = *(const float4*)&xb[row * CDIM + c4 * 4];
        pv.x = pk2(v.x, v.y);
        pv.y = pk2(v.z, v.w);
      }
      int byte = row * 512 + ((((c4 >> 1) ^ (row & 31)) << 4) | ((c4 & 1) << 3));
      *(uint2*)(base + byte) = pv;
    }
  }
  __syncthreads();

  // ---- fused Q+K GEMM, distance-2 rotating weight prefetch ----
  bf16x8 Qf[2][2], Kf[2][2];
  bf16x8 wvf[2];                            // V kc=0,1 pre-issued at loop end
  {
    f32x16 accQ0 = Z16, accQ1 = Z16, accK0 = Z16, accK1 = Z16;
    #pragma unroll
    for (int kc = 0; kc < 16; ++kc) {
      bf16x8 wq_c = wqf[kc & 1], wk_c = wkf[kc & 1];
      if (kc + 2 < 16) {                    // issue kc+2's frags before this iter's MFMAs
        wqf[kc & 1] = *(const bf16x8*)&wQb[(kc + 2) * 512 + fragoff];
        wkf[kc & 1] = *(const bf16x8*)&wKb[(kc + 2) * 512 + fragoff];
      }
      if (kc == 14) {                       // pre-issue V kc=0,1 (consumed after xchg section)
        wvf[0] = *(const bf16x8*)&wVb[0 * 512 + fragoff];
        wvf[1] = *(const bf16x8*)&wVb[1 * 512 + fragoff];
      }
      bf16x8 x0 = ld_tile(base, l31, kc, myh);
      bf16x8 x1 = ld_tile(base, 32 + l31, kc, myh);
      accQ0 = MFMA32(wq_c, x0, accQ0);
      accK0 = MFMA32(wk_c, x0, accK0);
      accQ1 = MFMA32(wq_c, x1, accQ1);
      accK1 = MFMA32(wk_c, x1, accK1);
    }
    #pragma unroll
    for (int r = 0; r < 16; ++r) {
      int f = (r & 3) + 8 * (r >> 2) + 4 * myh;
      float bq = qkv_b[w * 32 + f] * SCALE;
      float bk = qkv_b[CDIM + w * 32 + f];
      accQ0[r] += bq; accQ1[r] += bq;
      accK0[r] += bk; accK1[r] += bk;
    }
    uint2 pq[4], pk[4];
    #pragma unroll
    for (int gI = 0; gI < 4; ++gI) {
      pq[gI] = make_uint2(pk2(accQ0[4*gI], accQ0[4*gI+1]), pk2(accQ0[4*gI+2], accQ0[4*gI+3]));
      pk[gI] = make_uint2(pk2(accK0[4*gI], accK0[4*gI+1]), pk2(accK0[4*gI+2], accK0[4*gI+3]));
    }
    Qf[0][0] = xchg(pq[0], pq[1], myh);  Qf[0][1] = xchg(pq[2], pq[3], myh);
    Kf[0][0] = xchg(pk[0], pk[1], myh);  Kf[0][1] = xchg(pk[2], pk[3], myh);
    #pragma unroll
    for (int gI = 0; gI < 4; ++gI) {
      pq[gI] = make_uint2(pk2(accQ1[4*gI], accQ1[4*gI+1]), pk2(accQ1[4*gI+2], accQ1[4*gI+3]));
      pk[gI] = make_uint2(pk2(accK1[4*gI], accK1[4*gI+1]), pk2(accK1[4*gI+2], accK1[4*gI+3]));
    }
    Qf[1][0] = xchg(pq[0], pq[1], myh);  Qf[1][1] = xchg(pq[2], pq[3], myh);
    Kf[1][0] = xchg(pk[0], pk[1], myh);  Kf[1][1] = xchg(pk[2], pk[3], myh);
  }

  // ---- V GEMM (distance-2 prefetch; kc=0,1 already in flight) ----
  bf16x8 Vf[4];
  {
    f32x16 accV0 = Z16, accV1 = Z16;
    #pragma unroll
    for (int kc = 0; kc < 16; ++kc) {
      bf16x8 wv_c = wvf[kc & 1];
      if (kc + 2 < 16)
        wvf[kc & 1] = *(const bf16x8*)&wVb[(kc + 2) * 512 + fragoff];
      accV0 = MFMA32(ld_tile(base, l31, kc, myh), wv_c, accV0);
      accV1 = MFMA32(ld_tile(base, 32 + l31, kc, myh), wv_c, accV1);
    }
    float bv = qkv_b[2 * CDIM + w * 32 + l31];
    #pragma unroll
    for (int r = 0; r < 16; ++r) { accV0[r] += bv; accV1[r] += bv; }
    uint2 pv0[4], pv1[4];
    #pragma unroll
    for (int gI = 0; gI < 4; ++gI) {
      pv0[gI] = make_uint2(pk2(accV0[4*gI], accV0[4*gI+1]), pk2(accV0[4*gI+2], accV0[4*gI+3]));
      pv1[gI] = make_uint2(pk2(accV1[4*gI], accV1[4*gI+1]), pk2(accV1[4*gI+2], accV1[4*gI+3]));
    }
    Vf[0] = xchg(pv0[0], pv0[1], myh);  Vf[1] = xchg(pv0[2], pv0[3], myh);
    Vf[2] = xchg(pv1[0], pv1[1], myh);  Vf[3] = xchg(pv1[2], pv1[3], myh);
  }

  // ---- per query-tile: S^T = K*Q^T (+bias) -> softmax (lane-local) -> P -> O = P*V ----
  uint2 Opk[2][4];   // packed bf16 O-tiles, 16 VGPRs
  #pragma unroll
  for (int qt = 0; qt < 2; ++qt) {
    f32x16 s0 = Z16, s1 = Z16;
    s0 = MFMA32(Kf[0][0], Qf[qt][0], s0);  s0 = MFMA32(Kf[0][1], Qf[qt][1], s0);
    s1 = MFMA32(Kf[1][0], Qf[qt][0], s1);  s1 = MFMA32(Kf[1][1], Qf[qt][1], s1);
    // bias add (frag-ordered, coalesced dwordx4)
    #pragma unroll
    for (int kt = 0; kt < 2; ++kt) {
      const float* bT = biasT + (size_t)(((w * 2 + kt) * 2 + qt) * 1024);
      #pragma unroll
      for (int gI = 0; gI < 4; ++gI) {
        f32x4 bv = *(const f32x4*)&bT[(gI * 2 + myh) * 128 + l31 * 4];
        if (kt == 0) { s0[4*gI] += bv[0]; s0[4*gI+1] += bv[1]; s0[4*gI+2] += bv[2]; s0[4*gI+3] += bv[3]; }
        else         { s1[4*gI] += bv[0]; s1[4*gI+1] += bv[1]; s1[4*gI+2] += bv[2]; s1[4*gI+3] += bv[3]; }
      }
    }
    // softmax over 64 keys: 32 lane-local + one cross-half shfl
    float mx = -3e38f;
    #pragma unroll
    for (int r = 0; r < 16; ++r) { mx = fmaxf(mx, s0[r]); mx = fmaxf(mx, s1[r]); }
    mx = fmaxf(mx, __shfl_xor(mx, 32));
    float sum = 0.f;
    #pragma unroll
    for (int r = 0; r < 16; ++r) {
      float e0 = __expf(s0[r] - mx); s0[r] = e0; sum += e0;
      float e1 = __expf(s1[r] - mx); s1[r] = e1; sum += e1;
    }
    sum += __shfl_xor(sum, 32);
    float inv = 1.f / sum;
    uint2 pp0[4], pp1[4];
    #pragma unroll
    for (int gI = 0; gI < 4; ++gI) {
      pp0[gI] = make_uint2(pk2(s0[4*gI]*inv, s0[4*gI+1]*inv), pk2(s0[4*gI+2]*inv, s0[4*gI+3]*inv));
      pp1[gI] = make_uint2(pk2(s1[4*gI]*inv, s1[4*gI+1]*inv), pk2(s1[4*gI+2]*inv, s1[4*gI+3]*inv));
    }
    bf16x8 Pf0 = xchg(pp0[0], pp0[1], myh), Pf1 = xchg(pp0[2], pp0[3], myh);
    bf16x8 Pf2 = xchg(pp1[0], pp1[1], myh), Pf3 = xchg(pp1[2], pp1[3], myh);
    f32x16 o = Z16;
    o = MFMA32(Pf0, Vf[0], o);
    o = MFMA32(Pf1, Vf[1], o);
    o = MFMA32(Pf2, Vf[2], o);
    o = MFMA32(Pf3, Vf[3], o);
    // pack O to bf16 immediately: releases all f32 accumulators
    #pragma unroll
    for (int gI = 0; gI < 4; ++gI)
      Opk[qt][gI] = make_uint2(pk2(o[4*gI], o[4*gI+1]), pk2(o[4*gI+2], o[4*gI+3]));
  }

  // ---- pre-issue proj weight frags kc=0,1 (independent of O LDS writes; barrier drains) ----
  bf16x8 wpf[2];
  wpf[0] = *(const bf16x8*)&wPb[0 * 512 + fragoff];
  wpf[1] = *(const bf16x8*)&wPb[1 * 512 + fragoff];

  __syncthreads();   // all waves done reading x -> safe to overwrite with O
  // ---- O -> swizzled LDS tile (cols w*32 + l31), bf16 ----
  {
    const int slotbase = (w << 2) | (l31 >> 3);
    #pragma unroll
    for (int qt = 0; qt < 2; ++qt)
      #pragma unroll
      for (int gI = 0; gI < 4; ++gI) {
        const unsigned xv = Opk[qt][gI].x, yv = Opk[qt][gI].y;
        #pragma unroll
        for (int rr = 0; rr < 4; ++rr) {
          unsigned short val = (unsigned short)(((rr < 2 ? xv : yv) >> ((rr & 1) * 16)) & 0xffffu);
          int t = qt * 32 + rr + 8 * gI + 4 * myh;
          int byte = t * 512 + (((slotbase ^ (t & 31)) << 4) | ((l31 & 7) << 1));
          *(unsigned short*)(base + byte) = val;
        }
      }
  }
  __syncthreads();

  // ---- proj: out = O * Wp^T + pb (distance-2 prefetch); wave owns e-cols [32w,32w+32) ----
  f32x16 po0 = Z16, po1 = Z16;
  #pragma unroll
  for (int kc = 0; kc < 16; ++kc) {
    bf16x8 wp_c = wpf[kc & 1];
    if (kc + 2 < 16)
      wpf[kc & 1] = *(const bf16x8*)&wPb[(kc + 2) * 512 + fragoff];
    po0 = MFMA32(ld_tile(base, l31, kc, myh), wp_c, po0);
    po1 = MFMA32(ld_tile(base, 32 + l31, kc, myh), wp_c, po1);
  }
  const float pb = proj_b[w * 32 + l31];
  #pragma unroll
  for (int r = 0; r < 16; ++r) {
    int t0 = (r & 3) + 8 * (r >> 2) + 4 * myh;
    if (t0 < NTOK) out[((size_t)b * NTOK + t0) * CDIM + w * 32 + l31] = po0[r] + pb;
    int t1 = 32 + t0;
    if (t1 < NTOK) out[((size_t)b * NTOK + t1) * CDIM + w * 32 + l31] = po1[r] + pb;
  }
}

extern "C" void kernel_launch(void* const* d_in, const int* in_sizes, int n_in,
                              void* d_out, int out_size, void* d_ws, size_t ws_size,
                              hipStream_t stream) {
  const float* x          = (const float*)d_in[0];
  const float* qkv_w      = (const float*)d_in[1];
  const float* qkv_b      = (const float*)d_in[2];
  const float* proj_w     = (const float*)d_in[3];
  const float* proj_b     = (const float*)d_in[4];
  const float* bias_table = (const float*)d_in[5];
  const int*   rel_idx    = (const int*)d_in[6];

  unsigned short* wq = (unsigned short*)d_ws;          // 768*256 bf16, frag-ordered
  unsigned short* wp = wq + 768 * 256;                 // 256*256 bf16, frag-ordered
  float* biasT = (float*)(wp + 256 * 256);             // 32768 f32, frag-ordered

  prep_kernel<<<768, 256, 0, stream>>>(qkv_w, proj_w, bias_table, rel_idx, wq, wp, biasT);
  mhsa_kernel<<<2048, 512, 0, stream>>>(x, wq, wp, biasT, qkv_b, proj_b, (float*)d_out);
}